// Round 1
// baseline (118.177 us; speedup 1.0000x reference)
//
#include <hip/hip_runtime.h>

// out[c, y, w] = x[p, c, oy, ox]
//   iy = y / 126 (clamped to 8, never triggers for y<1024)
//   jx = w / 126
//   oy = y - iy*126, ox = w - jx*126
//   p  = iy*9 + jx
// x shape: (81, 64, 128, 128) f32; out shape: (64, 1024, 1024) f32.
// Pure gather, memory-bound. float4 stores, scalar gather loads
// (input segments are contiguous per jx-segment so lanes coalesce).

__global__ __launch_bounds__(256) void patch_gather_kernel(
    const float* __restrict__ x, float* __restrict__ out, unsigned n_groups) {
    const unsigned stride = gridDim.x * blockDim.x;
    for (unsigned g = blockIdx.x * blockDim.x + threadIdx.x; g < n_groups; g += stride) {
        const unsigned idx = g << 2;               // flat output index of first of 4
        const unsigned c  = idx >> 20;             // H*W = 2^20
        const unsigned y  = (idx >> 10) & 1023u;
        const unsigned w0 = idx & 1023u;           // multiple of 4, no row crossing

        const unsigned iy = y / 126u;              // 0..8 (magic-mul)
        const unsigned oy = y - iy * 126u;

        float v[4];
        #pragma unroll
        for (int k = 0; k < 4; ++k) {
            const unsigned w  = w0 + k;
            const unsigned jx = w / 126u;          // 0..8
            const unsigned ox = w - jx * 126u;
            const unsigned p  = iy * 9u + jx;
            // ((p*64 + c) * 128 + oy) * 128 + ox
            const size_t addr = ((size_t)(p * 64u + c) << 14) + (oy << 7) + ox;
            v[k] = x[addr];
        }
        float4 r;
        r.x = v[0]; r.y = v[1]; r.z = v[2]; r.w = v[3];
        *reinterpret_cast<float4*>(&out[idx]) = r;
    }
}

extern "C" void kernel_launch(void* const* d_in, const int* in_sizes, int n_in,
                              void* d_out, int out_size, void* d_ws, size_t ws_size,
                              hipStream_t stream) {
    const float* x = (const float*)d_in[0];
    float* out = (float*)d_out;

    const unsigned n_groups = (unsigned)(out_size / 4);   // 16,777,216
    const int block = 256;
    // Guideline 11: cap grid ~2048 blocks, grid-stride the rest.
    unsigned total_blocks = (n_groups + block - 1) / block;
    unsigned grid = total_blocks < 2048u ? total_blocks : 2048u;

    patch_gather_kernel<<<grid, block, 0, stream>>>(x, out, n_groups);
}